// Round 4
// baseline (82.226 us; speedup 1.0000x reference)
//
#include <hip/hip_runtime.h>
#include <hip/hip_bf16.h>
#include <math.h>

#define N_AUDIO 32768
#define NB 8
#define NC 128
#define NT 128
#define NO 128

// ws layout:
//   SEG : float4[NB][NT][NO]  (f/2, df/1024, a/128, da/128)  = 2 MiB
//   CW  : float [NB][NT][NO]  ((C_i/2) mod 1, revolutions)   = 512 KiB
// z_rev(m) = CW + m*(f/2) + m^2*(df/1024); audio = sum_o amp'(m)*sin(2*pi*fract(z_rev))

__global__ __launch_bounds__(128)
void prep_kernel(const float* __restrict__ x,
                 const float* __restrict__ amp_w,
                 const float* __restrict__ amp_b,
                 const float* __restrict__ freq_w,
                 const float* __restrict__ freq_b,
                 float4* __restrict__ SEG,
                 float*  __restrict__ CW)
{
    const int bo = blockIdx.x;            // 0..1023
    const int b  = bo >> 7;
    const int o  = bo & 127;
    const int t  = threadIdx.x;           // knot index 0..127

    const float* xp = x + b * (NC * NT) + t;   // x[b, c, t], stride NT per c
    const float* wa = amp_w  + o * NC;
    const float* wf = freq_w + o * NC;

    float va = 0.f, vf = 0.f;
#pragma unroll 8
    for (int c = 0; c < NC; ++c) {
        float xv = xp[c * NT];
        va = fmaf(xv, wa[c], va);
        vf = fmaf(xv, wf[c], vf);
    }
    va += amp_b[o];
    vf += freq_b[o];
    const float sa = 1.f / (1.f + __expf(-va));   // amp knot
    const float sf = 1.f / (1.f + __expf(-vf));   // freq knot

    __shared__ float  fsh[NT];
    __shared__ float  ash[NT];
    __shared__ double psh[NT];
    fsh[t] = sf;
    ash[t] = sa;
    psh[t] = (double)sf;
    __syncthreads();

    // Hillis-Steele inclusive scan (double) over the 128 freq knots
    for (int off = 1; off < NT; off <<= 1) {
        double add = (t >= off) ? psh[t - off] : 0.0;
        double v   = psh[t];
        __syncthreads();
        psh[t] = v + add;
        __syncthreads();
    }
    const double incl = psh[t];
    const double excl = incl - (double)sf;
    // C_i (rev) = 128 * sum_{s<i} f_s + 64 * f_i  (phase/2pi at segment start)
    double Cd = 128.0 * excl + 64.0 * (double)sf;
    Cd -= floor(Cd);                      // mod 1 revolution

    const float df = (t < NT - 1) ? (fsh[t + 1] - sf) : 0.f;
    const float da = (t < NT - 1) ? (ash[t + 1] - sa) : 0.f;

    const int idx = (b * NT + t) * NO + o;   // [b][i][o] layout
    SEG[idx] = make_float4(0.5f * sf,              // m coefficient (rev)
                           df * (1.f / 1024.f),    // m^2 coefficient (rev)
                           sa * (1.f / 128.f),     // amp / 128 (mean folded in)
                           da * (1.f / 128.f));    // damp / 128
    CW[idx]  = (float)Cd;
}

__global__ __launch_bounds__(256)
void synth_kernel(const float4* __restrict__ SEG,
                  const float*  __restrict__ CW,
                  float* __restrict__ out)
{
    const int k   = blockIdx.x;           // 0..127: samples [256k, 256k+256)
    const int b   = blockIdx.y;
    const int tid = threadIdx.x;
    const int j   = k * 256 + tid;

    // Each wave's 64 consecutive samples lie in ONE segment row (boundaries at
    // j = 128+256i are 64-aligned). Force the row index scalar so the per-osc
    // param reads become s_load (SMEM pipe) — no VMEM/LDS data-return cost.
    const int wid   = __builtin_amdgcn_readfirstlane(tid >> 6);   // 0..3
    const int start = k * 256 + wid * 64;                          // wave-uniform
    const int head  = (start < 128) ? 1 : 0;                       // clipped head
    const int r     = head ? 0 : ((start - 128) >> 8);             // segment row
    const float mask = head ? 0.f : 1.f;

    const float m  = (float)(j - 127 - (r << 8));     // per-lane sample offset
    const float m2 = m * m * mask;                    // kills quadratic in head
    const float wA = (m - 0.5f) * (1.f / 256.f) * mask;

    const int base = __builtin_amdgcn_readfirstlane((b * NT + r) * NO);
    const float4* __restrict__ P = SEG + base;
    const float*  __restrict__ C = CW  + base;

    float acc0 = 0.f, acc1 = 0.f;
#pragma unroll 4
    for (int o = 0; o < NO; o += 2) {
        const float4 p0 = P[o];       // wave-uniform -> s_load_dwordx4
        const float4 p1 = P[o + 1];
        const float  c0 = C[o];
        const float  c1 = C[o + 1];
        // every VALU op reads at most ONE scalar operand (no v_mov fixups)
        float z0 = m * p0.x;  z0 += c0;  z0 = fmaf(m2, p0.y, z0);  // revolutions
        float z1 = m * p1.x;  z1 += c1;  z1 = fmaf(m2, p1.y, z1);
        float a0 = wA * p0.w; a0 += p0.z;
        float a1 = wA * p1.w; a1 += p1.z;
        acc0 = fmaf(a0, __builtin_amdgcn_sinf(__builtin_amdgcn_fractf(z0)), acc0);
        acc1 = fmaf(a1, __builtin_amdgcn_sinf(__builtin_amdgcn_fractf(z1)), acc1);
    }
    out[b * N_AUDIO + j] = acc0 + acc1;
}

extern "C" void kernel_launch(void* const* d_in, const int* in_sizes, int n_in,
                              void* d_out, int out_size, void* d_ws, size_t ws_size,
                              hipStream_t stream)
{
    const float* x      = (const float*)d_in[0];
    const float* amp_w  = (const float*)d_in[1];
    const float* amp_b  = (const float*)d_in[2];
    const float* freq_w = (const float*)d_in[3];
    const float* freq_b = (const float*)d_in[4];
    float* out = (float*)d_out;

    float4* SEG = (float4*)d_ws;
    float*  CW  = (float*)((char*)d_ws + (size_t)NB * NT * NO * sizeof(float4));

    prep_kernel<<<dim3(NB * NO), dim3(128), 0, stream>>>(
        x, amp_w, amp_b, freq_w, freq_b, SEG, CW);
    synth_kernel<<<dim3(N_AUDIO / 256, NB), dim3(256), 0, stream>>>(SEG, CW, out);
}